// Round 6
// baseline (173.172 us; speedup 1.0000x reference)
//
#include <hip/hip_runtime.h>

// Problem constants
//   m1:(1,1,4096,64) m2:(1,1,6144,64) m3:(1,1,8192,64) m4:(1,1,4096,64) fp32
//   WQ_w:(3,64,64) WQ_b:(3,64) WK_w:(4,3,64,64) WK_b:(4,3,64)
//   out:(1,4096,32) fp32
//
// ONE dispatch, 512 blocks x 256 (3 blocks/CU by LDS -> capacity 768, all
// co-resident => flag barrier cannot deadlock; cg grid.sync measured
// ~75us/sync in R1 and is NOT used):
//   Phase A (blocks 0..415): MLPs + bf16 Q/K stores + bf16 chunk K^T.V sums
//            + bf16 V^T store + t2 dense + zero out; publish per-chunk/tile
//            MAGIC flag (__threadfence_system -> L2 writeback -> system-scope
//            release store).
//   Phase C (all 512 blocks): spin with system-scope acquire loads on exactly
//            the flags this query block needs, then searchsorted + S-prefix
//            column-sum + boundary-chunk masked attention + atomicAdd.
//
// R4/R5 ROOT CAUSE (identical absmax 41472 across different fence codes =>
// deterministic logic bug, NOT coherence): the merge re-added
// `if (slot==1 && B0+1>=Bhi) return;` from the R0/R1 architecture. Since R2
// the S-prefix is DISTRIBUTED: slot-1 owns the odd-indexed chunk sums < B0
// and must always run prefix + Q.S + atomicAdd even with no boundary chunks.
// That return dropped half the prefix for most tiles. REMOVED here (R3, the
// verified 98.3us two-kernel version, has no such return).
//
// Flags need no init: byte-repeated poison != 4-distinct-byte MAGIC, and the
// computation is bit-deterministic per iteration so a stale-MAGIC pass still
// reads identical bits.
//
// Workspace layout (float units):
//   Qb   bf16 [4096][64]                 @ 0          (131072 fl)
//   Kb   bf16 per module [T_m][64]       @ 131072     (720896 fl)
//   SP   bf16 352 slots x 2048 (d*32+e)  @ 851968     (360448 fl)
//   VB   bf16 352 slots x 2048 (e*64+j)  @ 1212416    (360448 fl)
//   TD   fp32 dense t2 per module        @ 1581056    (22528 fl)
//   FL   u32 flags [64 qtile][352 chunk] @ 1603584    (416)

#define QB_OFF   0
#define KB_OFF   131072
#define SP_OFF   851968
#define VB_OFF   1212416
#define TD_OFF   1581056
#define FL_OFF   1603584
#define MAGIC    0x9E3779B1u

typedef __attribute__((ext_vector_type(8))) short short8;    // bf16 frag (4 VGPR)
typedef __attribute__((ext_vector_type(4))) float floatx4;   // MFMA C/D

__device__ __forceinline__ unsigned short f2bf(float f) {
    union { float f; unsigned u; } v; v.f = f;
    unsigned r = v.u + 0x7fff + ((v.u >> 16) & 1);   // RNE
    return (unsigned short)(r >> 16);
}
__device__ __forceinline__ float bf2f(unsigned short h) {
    union { unsigned u; float f; } v; v.u = ((unsigned)h) << 16;
    return v.f;
}

#define MFMA16(a,b,c) __builtin_amdgcn_mfma_f32_16x16x32_bf16((a),(b),(c),0,0,0)

// One 64x64 MLP layer: Hout = act(Hin @ W + b); optional K^T mirror.
__device__ __forceinline__ void mlp_layer(
    const unsigned short* Hin, unsigned short* Hout,
    const unsigned short* Wl, float bias, bool relu,
    unsigned short* KTopt, int col, int lm, int q)
{
    short8 b0 = *(const short8*)&Wl[col*72 + q*8];
    short8 b1 = *(const short8*)&Wl[col*72 + 32 + q*8];
    #pragma unroll
    for (int mt = 0; mt < 4; ++mt) {
        floatx4 acc = {bias, bias, bias, bias};
        short8 a0 = *(const short8*)&Hin[(mt*16+lm)*72 + q*8];
        short8 a1 = *(const short8*)&Hin[(mt*16+lm)*72 + 32 + q*8];
        acc = MFMA16(a0, b0, acc);
        acc = MFMA16(a1, b1, acc);
        int r0 = mt*16 + q*4;
        #pragma unroll
        for (int r = 0; r < 4; ++r) {
            float f = acc[r];
            if (relu) f = fmaxf(f, 0.0f);
            unsigned short hb = f2bf(f);
            Hout[(r0+r)*72 + col] = hb;
            if (KTopt) KTopt[col*72 + r0 + r] = hb;   // K^T [d][j]
        }
    }
}

__global__ __launch_bounds__(256, 3) void k_all(
    const float* __restrict__ x0, const float* __restrict__ x1,
    const float* __restrict__ x2, const float* __restrict__ x3,
    const float* __restrict__ wq_w, const float* __restrict__ wq_b,
    const float* __restrict__ wk_w, const float* __restrict__ wk_b,
    float* __restrict__ ws, float* __restrict__ out)
{
    // 50688 B overlay + 528 B floats = 51.2 KB -> 3 blocks/CU
    __shared__ unsigned short SH[25344];
    __shared__ float SF[130];     // tq[64] | tcs[64] | 2 spare
    __shared__ int   SB[2];       // c_lo, c_hi

    const int tid = threadIdx.x;
    const int bid = blockIdx.x;

    const int w    = tid >> 6;
    const int lane = tid & 63;
    const int lm   = lane & 15;
    const int q    = lane >> 4;
    const int col  = w*16 + lm;

    const float* Xs[4] = {x0, x1, x2, x3};
    const int rowoff[4] = {0, 4096, 10240, 18432};
    const int spoffc[4] = {0, 64, 160, 288};
    const int nchv[4]   = {64, 96, 128, 64};
    const int Tm[4]     = {4096, 6144, 8192, 4096};

    unsigned* flags = (unsigned*)(ws + FL_OFF);

    // ================= Phase A: fused MLP + chunk sums =================
    if (bid < 416) {
        unsigned short* H0  = SH;              // act ping [row][col]
        unsigned short* H1  = SH + 4608;       // act pong
        unsigned short* Wt0 = SH + 9216;       // W^T buf0 (layers 0, then 2)
        unsigned short* Wt1 = SH + 13824;      // W^T buf1 (layer 1)
        unsigned short* KT  = SH + 18432;      // K^T [d][j]
        unsigned short* VT  = SH + 23040;      // V^T [e][j] (2304)

        int task, rb;
        if (bid < 64)       { task = 0; rb = bid; }
        else if (bid < 128) { task = 1; rb = bid - 64; }
        else if (bid < 224) { task = 2; rb = bid - 128; }
        else if (bid < 352) { task = 3; rb = bid - 224; }
        else                { task = 4; rb = bid - 352; }

        const float* X; const float* W; const float* Bv; int mm = -1;
        if (task == 0) { X = x0; W = wq_w; Bv = wq_b; }
        else {
            mm = task - 1;
            X = Xs[mm]; W = wk_w + mm*3*64*64; Bv = wk_b + mm*3*64;
        }

        const int row0 = rb * 64;

        // one up-front register batch: X tile + all 3 W layers + biases
        float4 xv[4];
        float4 wv[12];
        {
            const float4* X4 = (const float4*)(X + (size_t)row0*64);
            #pragma unroll
            for (int k = 0; k < 4; ++k) xv[k] = X4[k*256 + tid];
            const float4* W4 = (const float4*)W;
            #pragma unroll
            for (int k = 0; k < 12; ++k) wv[k] = W4[k*256 + tid];
        }
        float bias0 = Bv[col], bias1 = Bv[64 + col], bias2 = Bv[128 + col];

        // X -> H0 [row][col] bf16; V^T [e][j] for e<32 from the same regs
        #pragma unroll
        for (int k = 0; k < 4; ++k) {
            int idx = k*256 + tid;
            int rr = idx >> 4, c4 = (idx & 15) * 4;
            ushort4 h;
            h.x = f2bf(xv[k].x); h.y = f2bf(xv[k].y);
            h.z = f2bf(xv[k].z); h.w = f2bf(xv[k].w);
            *(ushort4*)&H0[rr*72 + c4] = h;
            if (task > 0 && c4 < 32) {
                VT[(c4+0)*72 + rr] = h.x;
                VT[(c4+1)*72 + rr] = h.y;
                VT[(c4+2)*72 + rr] = h.z;
                VT[(c4+3)*72 + rr] = h.w;
            }
        }
        // W layers 0,1 -> Wt0,Wt1 (layer 2 regs wv[8..11] staged later)
        #pragma unroll
        for (int k = 0; k < 8; ++k) {
            int idx = k*256 + tid;
            int rest = idx & 1023;
            int d = rest >> 4, c4 = (rest & 15) * 4;
            unsigned short* Wl = (idx >> 10) ? Wt1 : Wt0;
            Wl[(c4+0)*72 + d] = f2bf(wv[k].x);
            Wl[(c4+1)*72 + d] = f2bf(wv[k].y);
            Wl[(c4+2)*72 + d] = f2bf(wv[k].z);
            Wl[(c4+3)*72 + d] = f2bf(wv[k].w);
        }
        // task-0 blocks zero the output region for their tile
        if (task == 0) {
            float4 z = make_float4(0.f, 0.f, 0.f, 0.f);
            ((float4*)out)[bid*512 + tid] = z;
            ((float4*)out)[bid*512 + 256 + tid] = z;
        }
        // dense timestamps (fp32, never through bf16)
        if (task > 0 && tid < 64)
            ws[TD_OFF + rowoff[mm] + row0 + tid] = X[(size_t)(row0 + tid)*64 + 63];
        __syncthreads();

        // fire-and-forget V^T chunk store (bf16); hides under MFMA layers
        if (task > 0) {
            unsigned short* VBg = (unsigned short*)(ws + VB_OFF)
                                + (size_t)(spoffc[mm] + rb) * 2048;
            #pragma unroll
            for (int k = 0; k < 2; ++k) {
                int p = k*256 + tid;
                int e = p >> 4, j4 = (p & 15) * 4;
                *(ushort4*)&VBg[p*4] = *(ushort4*)&VT[e*72 + j4];
            }
        }

        // layer 0: H0 -> H1 (Wt0)
        mlp_layer(H0, H1, Wt0, bias0, true, nullptr, col, lm, q);
        __syncthreads();

        // stage layer-2 W into Wt0 (all reads of layer-0 W are done)
        #pragma unroll
        for (int k = 0; k < 4; ++k) {
            int idx = k*256 + tid;
            int rest = idx & 1023;
            int d = rest >> 4, c4 = (rest & 15) * 4;
            Wt0[(c4+0)*72 + d] = f2bf(wv[8+k].x);
            Wt0[(c4+1)*72 + d] = f2bf(wv[8+k].y);
            Wt0[(c4+2)*72 + d] = f2bf(wv[8+k].z);
            Wt0[(c4+3)*72 + d] = f2bf(wv[8+k].w);
        }
        // layer 1: H1 -> H0 (Wt1)
        mlp_layer(H1, H0, Wt1, bias1, true, nullptr, col, lm, q);
        __syncthreads();

        // layer 2: H0 -> H1 (Wt0), mirror K^T for chunk sum
        mlp_layer(H0, H1, Wt0, bias2, false, (task > 0) ? KT : nullptr,
                  col, lm, q);
        __syncthreads();

        // coalesced bf16 global store of final activations (H1)
        {
            unsigned short* dst = (task == 0)
                ? (unsigned short*)(ws + QB_OFF)
                : (unsigned short*)(ws + KB_OFF) + (size_t)rowoff[mm]*64;
            #pragma unroll
            for (int k = 0; k < 4; ++k) {
                int idx = k*256 + tid;
                int rr = idx >> 4, c4 = (idx & 15) * 4;
                *(ushort4*)&dst[(size_t)(row0 + rr)*64 + c4] = *(ushort4*)&H1[rr*72 + c4];
            }
        }

        // chunk sum S[d][e] = sum_j K[j][d] V[j][e]; wave w owns d-tile w
        if (task > 0) {
            unsigned short* slotH = (unsigned short*)(ws + SP_OFF)
                                  + (size_t)(spoffc[mm] + rb) * 2048;
            #pragma unroll
            for (int nt = 0; nt < 2; ++nt) {
                floatx4 acc = {0.f, 0.f, 0.f, 0.f};
                #pragma unroll
                for (int ks = 0; ks < 2; ++ks) {
                    short8 aa = *(const short8*)&KT[col*72 + ks*32 + q*8];
                    short8 bb = *(const short8*)&VT[(nt*16+lm)*72 + ks*32 + q*8];
                    acc = MFMA16(aa, bb, acc);
                }
                #pragma unroll
                for (int r = 0; r < 4; ++r)
                    slotH[(w*16 + q*4 + r)*32 + nt*16 + lm] = f2bf(acc[r]);
            }
        }

        // publish: __syncthreads drains all block stores into this XCD's L2
        // (vmcnt(0) before s_barrier); __threadfence_system() writes the L2
        // back to the device coherence point so other XCDs see the DATA;
        // then SYSTEM-scope release flag store.
        __syncthreads();
        if (tid == 0) {
            __threadfence_system();
            int fi = (task == 0) ? bid : (64 + spoffc[mm] + rb);
            __hip_atomic_store(&flags[fi], MAGIC, __ATOMIC_RELEASE,
                               __HIP_MEMORY_SCOPE_SYSTEM);
        }
    }

    // ================= Phase C: tiled MFMA query =================
    {
        unsigned short* qs = SH;                 // Q  [i][d]
        unsigned short* kc = SH + 4608;          // K  [j][d]  (chunk)
        unsigned short* ps = SH + 9216;          // masked P [i][j]
        unsigned short* vt = SH + 13824;         // V^T [e][j] (2304)
        unsigned short* st = SH + 16128;         // S^T [e][d] (2304)
        float* tq  = SF;                         // t1 tile (fp32!)
        float* tcs = SF + 64;                    // t2 chunk (fp32!)

        const int m    = bid & 3;
        const int tile = (bid >> 2) & 63;
        const int slot = bid >> 8;               // 0 or 1
        const int i0   = tile * 64;
        const int nch  = nchv[m];

        // spin only on the flags this block needs:
        //   tid<nch          -> chunk flags of module m (covers Kb/SP/VB/TD_m)
        //   tid==254         -> qflag[tile] (Q rows + out-zero of this tile)
        //   tid==255         -> m1 chunk flag[tile] (t1/TD region)
        {
            int fidx = -1;
            if (tid < nch)       fidx = 64 + spoffc[m] + tid;
            else if (tid == 254) fidx = tile;
            else if (tid == 255) fidx = 64 + tile;
            bool ok = (fidx < 0);
            while (true) {
                if (!ok && __hip_atomic_load(&flags[fidx], __ATOMIC_ACQUIRE,
                                             __HIP_MEMORY_SCOPE_SYSTEM) == MAGIC)
                    ok = true;
                if (__syncthreads_and(ok ? 1 : 0)) break;
                __builtin_amdgcn_s_sleep(8);
            }
            __threadfence();   // order data loads after the spin exit
        }

        const unsigned short* Qg  = (const unsigned short*)(ws + QB_OFF);
        const unsigned short* Kg  = (const unsigned short*)(ws + KB_OFF) + (size_t)rowoff[m]*64;
        const unsigned short* SPH = (const unsigned short*)(ws + SP_OFF);
        const unsigned short* VBH = (const unsigned short*)(ws + VB_OFF);
        const float* td = ws + TD_OFF;

        // Q tile -> LDS
        #pragma unroll
        for (int k = 0; k < 4; ++k) {
            int idx = k*256 + tid;
            int rr = idx >> 4, c4 = (idx & 15) * 4;
            *(ushort4*)&qs[rr*72 + c4] = *(const ushort4*)&Qg[(size_t)(i0 + rr)*64 + c4];
        }
        if (tid < 64) tq[tid] = td[i0 + tid];

        // wave-parallel 64-ary searchsorted(t2, t, side='right'):
        // wave0 -> c_lo (t = t1[i0]), wave1 -> c_hi (t = t1[i0+63]).
        if (w < 2) {
            float t = td[i0 + (w ? 63 : 0)];
            const float* t2 = td + rowoff[m];
            int lo = 0, hi = Tm[m];
            while (hi - lo > 64) {
                int step = (hi - lo + 63) >> 6;
                int pos = lo + lane*step;
                bool pred = (pos < hi) && (t2[pos] <= t);
                int c = __popcll(__ballot(pred));
                int nhi = (c < 64) ? (lo + c*step) : hi;
                if (nhi > hi) nhi = hi;
                if (c) lo = lo + (c-1)*step + 1;
                hi = nhi;
            }
            int pos = lo + lane;
            bool pred = (pos < hi) && (t2[pos] <= t);
            int c = __popcll(__ballot(pred));
            if (lane == 0) SB[w] = lo + c;
        }
        __syncthreads();

        const int c_lo = SB[0];
        const int c_hi = SB[1];
        const int B0   = c_lo >> 6;
        const int Bhi  = (c_hi + 63) >> 6;

        // NOTE: no slot-1 early return here! Slot-1 owns the odd-indexed
        // half of the distributed S-prefix (R4/R5 bug).

        // on-the-fly S-prefix: sum chunk slots {slot, slot+2, ...} < B0.
        // Thread owns 8 consecutive entries (one uint4 per slot); 8 in flight.
        {
            float sacc[8] = {0.f,0.f,0.f,0.f,0.f,0.f,0.f,0.f};
            const unsigned short* sp0 = SPH + (size_t)spoffc[m]*2048 + tid*8;
#define ACC8(pv) do { \
            sacc[0] += bf2f((unsigned short)((pv).x & 0xffffu)); \
            sacc[1] += bf2f((unsigned short)((pv).x >> 16)); \
            sacc[2] += bf2f((unsigned short)((pv).y & 0xffffu)); \
            sacc[3] += bf2f((unsigned short)((pv).y >> 16)); \
            sacc[4] += bf2f((unsigned short)((pv).z & 0xffffu)); \
            sacc[5] += bf2f((unsigned short)((pv).z >> 16)); \
            sacc[6] += bf2f((unsigned short)((pv).w & 0xffffu)); \
            sacc[7] += bf2f((unsigned short)((pv).w >> 16)); \
        } while (0)
            int k = slot;
            for (; k + 14 < B0; k += 16) {
                uint4 p0 = *(const uint4*)(sp0 + (size_t)(k   )*2048);
                uint4 p1 = *(const uint4*)(sp0 + (size_t)(k+ 2)*2048);
                uint4 p2 = *(const uint4*)(sp0 + (size_t)(k+ 4)*2048);
                uint4 p3 = *(const uint4*)(sp0 + (size_t)(k+ 6)*2048);
                uint4 p4 = *(const uint4*)(sp0 + (size_t)(k+ 8)*2048);
                uint4 p5 = *(const uint4*)(sp0 + (size_t)(k+10)*2048);
                uint4 p6 = *(const uint4*)(sp0 + (size_t)(k+12)*2048);
                uint4 p7 = *(const uint4*)(sp0 + (size_t)(k+14)*2048);
                ACC8(p0); ACC8(p1); ACC8(p2); ACC8(p3);
                ACC8(p4); ACC8(p5); ACC8(p6); ACC8(p7);
            }
            for (; k + 6 < B0; k += 8) {
                uint4 p0 = *(const uint4*)(sp0 + (size_t)(k  )*2048);
                uint4 p1 = *(const uint4*)(sp0 + (size_t)(k+2)*2048);
                uint4 p2 = *(const uint4*)(sp0 + (size_t)(k+4)*2048);
                uint4 p3 = *(const uint4*)(sp0 + (size_t)(k+6)*2048);
                ACC8(p0); ACC8(p1); ACC8(p2); ACC8(p3);
            }
            for (; k < B0; k += 2) {
                uint4 p0 = *(const uint4*)(sp0 + (size_t)k*2048);
                ACC8(p0);
            }
#undef ACC8
            int d0 = (tid*8) >> 5, e0 = (tid*8) & 31;
            #pragma unroll
            for (int k2 = 0; k2 < 8; ++k2)
                st[(e0+k2)*72 + d0] = f2bf(sacc[k2]);
        }
        __syncthreads();

        float t1v[16];
        #pragma unroll
        for (int mt = 0; mt < 4; ++mt)
            #pragma unroll
            for (int r = 0; r < 4; ++r)
                t1v[mt*4 + r] = tq[mt*16 + q*4 + r];

        short8 qa[4][2];
        #pragma unroll
        for (int mt = 0; mt < 4; ++mt) {
            qa[mt][0] = *(const short8*)&qs[(mt*16+lm)*72 + q*8];
            qa[mt][1] = *(const short8*)&qs[(mt*16+lm)*72 + 32 + q*8];
        }

        floatx4 accO[2];
        accO[0] = (floatx4){0.f, 0.f, 0.f, 0.f};
        accO[1] = (floatx4){0.f, 0.f, 0.f, 0.f};

        // Q . S_partial (both slots; each holds its half of the prefix)
        #pragma unroll
        for (int nt = 0; nt < 2; ++nt) {
            #pragma unroll
            for (int ks = 0; ks < 2; ++ks) {
                short8 b = *(const short8*)&st[(nt*16+lm)*72 + ks*32 + q*8];
                accO[nt] = MFMA16(qa[w][ks], b, accO[nt]);
            }
        }

        // boundary chunks: masked attention, odd/even split across slots
        // (loop is naturally empty for slot-1 blocks with <2 boundary chunks)
        #pragma unroll 1
        for (int B = B0 + slot; B < Bhi; B += 2) {
            __syncthreads();
            #pragma unroll
            for (int k = 0; k < 4; ++k) {
                int idx = k*256 + tid;
                int j = idx >> 4, c4 = (idx & 15) * 4;
                *(ushort4*)&kc[j*72 + c4] = *(const ushort4*)&Kg[(size_t)(B*64 + j)*64 + c4];
            }
            {
                const unsigned short* VBg = VBH + (size_t)(spoffc[m] + B)*2048;
                #pragma unroll
                for (int k = 0; k < 2; ++k) {
                    int p = k*256 + tid;
                    int e = p >> 4, j4 = (p & 15) * 4;
                    *(ushort4*)&vt[e*72 + j4] = *(const ushort4*)&VBg[p*4];
                }
            }
            if (tid < 64) tcs[tid] = td[rowoff[m] + B*64 + tid];
            __syncthreads();

            {
                short8 bk0 = *(const short8*)&kc[(w*16+lm)*72 + q*8];
                short8 bk1 = *(const short8*)&kc[(w*16+lm)*72 + 32 + q*8];
                float t2j = tcs[w*16 + lm];
                #pragma unroll
                for (int mt = 0; mt < 4; ++mt) {
                    floatx4 f = {0.f, 0.f, 0.f, 0.f};
                    f = MFMA16(qa[mt][0], bk0, f);
                    f = MFMA16(qa[mt][1], bk1, f);
                    #pragma unroll
                    for (int r = 0; r < 4; ++r) {
                        float pv = (t2j <= t1v[mt*4 + r]) ? f[r] : 0.0f;
                        ps[(mt*16 + q*4 + r)*72 + w*16 + lm] = f2bf(pv);
                    }
                }
            }
            __syncthreads();

            {
                short8 pa0 = *(const short8*)&ps[(w*16+lm)*72 + q*8];
                short8 pa1 = *(const short8*)&ps[(w*16+lm)*72 + 32 + q*8];
                #pragma unroll
                for (int nt = 0; nt < 2; ++nt) {
                    short8 bv0 = *(const short8*)&vt[(nt*16+lm)*72 + q*8];
                    short8 bv1 = *(const short8*)&vt[(nt*16+lm)*72 + 32 + q*8];
                    accO[nt] = MFMA16(pa0, bv0, accO[nt]);
                    accO[nt] = MFMA16(pa1, bv1, accO[nt]);
                }
            }
        }

        #pragma unroll
        for (int nt = 0; nt < 2; ++nt)
            #pragma unroll
            for (int r = 0; r < 4; ++r) {
                int i = w*16 + q*4 + r;
                int e = nt*16 + lm;
                atomicAdd(&out[(size_t)(i0 + i)*32 + e], accO[nt][r]);
            }
    }
}

extern "C" void kernel_launch(void* const* d_in, const int* in_sizes, int n_in,
                              void* d_out, int out_size, void* d_ws, size_t ws_size,
                              hipStream_t stream) {
    const float* x0   = (const float*)d_in[0];
    const float* x1   = (const float*)d_in[1];
    const float* x2   = (const float*)d_in[2];
    const float* x3   = (const float*)d_in[3];
    const float* wq_w = (const float*)d_in[4];
    const float* wq_b = (const float*)d_in[5];
    const float* wk_w = (const float*)d_in[6];
    const float* wk_b = (const float*)d_in[7];
    float* ws  = (float*)d_ws;
    float* out = (float*)d_out;

    hipLaunchKernelGGL(k_all, dim3(512), dim3(256), 0, stream,
                       x0, x1, x2, x3, wq_w, wq_b, wk_w, wk_b, ws, out);
}

// Round 7
// 139.263 us; speedup vs baseline: 1.2435x; 1.2435x over previous
//
#include <hip/hip_runtime.h>

// Problem constants
//   m1:(1,1,4096,64) m2:(1,1,6144,64) m3:(1,1,8192,64) m4:(1,1,4096,64) fp32
//   WQ_w:(3,64,64) WQ_b:(3,64) WK_w:(4,3,64,64) WK_b:(4,3,64)
//   out:(1,4096,32) fp32
//
// ONE dispatch, 512 blocks x 256 (3 blocks/CU by LDS -> capacity 768, all
// co-resident => flag barrier cannot deadlock).
//
// SYNC PROTOCOL (R6 lesson): per-iteration ACQUIRE spin loads each emit a
// full L2 `buffer_inv` on gfx950 -> millions of L2-wide invalidates starved
// the whole chip (k_all 107us, 227GB/s churn). Correct minimal protocol:
//   Producer: __syncthreads (drains stores to L2) -> ONE agent-scope RELEASE
//             store of MAGIC (release itself performs the dirty-L2 writeback
//             to the LLC; no extra __threadfence_system).
//   Consumer: spin with RELAXED agent-scope loads (coherent-bypass reads of
//             the LLC, no cache ops), then ONE __threadfence() (acquire ->
//             single buffer_inv) per block after __syncthreads_and exit.
// R4 empirically validated this light protocol's visibility (its failure was
// the slot-1 early-return logic bug, fixed in R6 and kept fixed here).
//
// Flags need no init: byte-repeated poison != 4-distinct-byte MAGIC, and the
// computation is bit-deterministic per iteration so a stale-MAGIC pass still
// reads identical bits.
//
// Workspace layout (float units):
//   Qb   bf16 [4096][64]                 @ 0          (131072 fl)
//   Kb   bf16 per module [T_m][64]       @ 131072     (720896 fl)
//   SP   bf16 352 slots x 2048 (d*32+e)  @ 851968     (360448 fl)
//   VB   bf16 352 slots x 2048 (e*64+j)  @ 1212416    (360448 fl)
//   TD   fp32 dense t2 per module        @ 1581056    (22528 fl)
//   FL   u32 flags [64 qtile][352 chunk] @ 1603584    (416)

#define QB_OFF   0
#define KB_OFF   131072
#define SP_OFF   851968
#define VB_OFF   1212416
#define TD_OFF   1581056
#define FL_OFF   1603584
#define MAGIC    0x9E3779B1u

typedef __attribute__((ext_vector_type(8))) short short8;    // bf16 frag (4 VGPR)
typedef __attribute__((ext_vector_type(4))) float floatx4;   // MFMA C/D

__device__ __forceinline__ unsigned short f2bf(float f) {
    union { float f; unsigned u; } v; v.f = f;
    unsigned r = v.u + 0x7fff + ((v.u >> 16) & 1);   // RNE
    return (unsigned short)(r >> 16);
}
__device__ __forceinline__ float bf2f(unsigned short h) {
    union { unsigned u; float f; } v; v.u = ((unsigned)h) << 16;
    return v.f;
}

#define MFMA16(a,b,c) __builtin_amdgcn_mfma_f32_16x16x32_bf16((a),(b),(c),0,0,0)

// One 64x64 MLP layer: Hout = act(Hin @ W + b); optional K^T mirror.
__device__ __forceinline__ void mlp_layer(
    const unsigned short* Hin, unsigned short* Hout,
    const unsigned short* Wl, float bias, bool relu,
    unsigned short* KTopt, int col, int lm, int q)
{
    short8 b0 = *(const short8*)&Wl[col*72 + q*8];
    short8 b1 = *(const short8*)&Wl[col*72 + 32 + q*8];
    #pragma unroll
    for (int mt = 0; mt < 4; ++mt) {
        floatx4 acc = {bias, bias, bias, bias};
        short8 a0 = *(const short8*)&Hin[(mt*16+lm)*72 + q*8];
        short8 a1 = *(const short8*)&Hin[(mt*16+lm)*72 + 32 + q*8];
        acc = MFMA16(a0, b0, acc);
        acc = MFMA16(a1, b1, acc);
        int r0 = mt*16 + q*4;
        #pragma unroll
        for (int r = 0; r < 4; ++r) {
            float f = acc[r];
            if (relu) f = fmaxf(f, 0.0f);
            unsigned short hb = f2bf(f);
            Hout[(r0+r)*72 + col] = hb;
            if (KTopt) KTopt[col*72 + r0 + r] = hb;   // K^T [d][j]
        }
    }
}

__global__ __launch_bounds__(256, 3) void k_all(
    const float* __restrict__ x0, const float* __restrict__ x1,
    const float* __restrict__ x2, const float* __restrict__ x3,
    const float* __restrict__ wq_w, const float* __restrict__ wq_b,
    const float* __restrict__ wk_w, const float* __restrict__ wk_b,
    float* __restrict__ ws, float* __restrict__ out)
{
    // 50688 B overlay + 528 B floats = 51.2 KB -> 3 blocks/CU
    __shared__ unsigned short SH[25344];
    __shared__ float SF[130];     // tq[64] | tcs[64] | 2 spare
    __shared__ int   SB[2];       // c_lo, c_hi

    const int tid = threadIdx.x;
    const int bid = blockIdx.x;

    const int w    = tid >> 6;
    const int lane = tid & 63;
    const int lm   = lane & 15;
    const int q    = lane >> 4;
    const int col  = w*16 + lm;

    const float* Xs[4] = {x0, x1, x2, x3};
    const int rowoff[4] = {0, 4096, 10240, 18432};
    const int spoffc[4] = {0, 64, 160, 288};
    const int nchv[4]   = {64, 96, 128, 64};
    const int Tm[4]     = {4096, 6144, 8192, 4096};

    unsigned* flags = (unsigned*)(ws + FL_OFF);

    // ================= Phase A: fused MLP + chunk sums =================
    if (bid < 416) {
        unsigned short* H0  = SH;              // act ping [row][col]
        unsigned short* H1  = SH + 4608;       // act pong
        unsigned short* Wt0 = SH + 9216;       // W^T buf0 (layers 0, then 2)
        unsigned short* Wt1 = SH + 13824;      // W^T buf1 (layer 1)
        unsigned short* KT  = SH + 18432;      // K^T [d][j]
        unsigned short* VT  = SH + 23040;      // V^T [e][j] (2304)

        int task, rb;
        if (bid < 64)       { task = 0; rb = bid; }
        else if (bid < 128) { task = 1; rb = bid - 64; }
        else if (bid < 224) { task = 2; rb = bid - 128; }
        else if (bid < 352) { task = 3; rb = bid - 224; }
        else                { task = 4; rb = bid - 352; }

        const float* X; const float* W; const float* Bv; int mm = -1;
        if (task == 0) { X = x0; W = wq_w; Bv = wq_b; }
        else {
            mm = task - 1;
            X = Xs[mm]; W = wk_w + mm*3*64*64; Bv = wk_b + mm*3*64;
        }

        const int row0 = rb * 64;

        // one up-front register batch: X tile + all 3 W layers + biases
        float4 xv[4];
        float4 wv[12];
        {
            const float4* X4 = (const float4*)(X + (size_t)row0*64);
            #pragma unroll
            for (int k = 0; k < 4; ++k) xv[k] = X4[k*256 + tid];
            const float4* W4 = (const float4*)W;
            #pragma unroll
            for (int k = 0; k < 12; ++k) wv[k] = W4[k*256 + tid];
        }
        float bias0 = Bv[col], bias1 = Bv[64 + col], bias2 = Bv[128 + col];

        // X -> H0 [row][col] bf16; V^T [e][j] for e<32 from the same regs
        #pragma unroll
        for (int k = 0; k < 4; ++k) {
            int idx = k*256 + tid;
            int rr = idx >> 4, c4 = (idx & 15) * 4;
            ushort4 h;
            h.x = f2bf(xv[k].x); h.y = f2bf(xv[k].y);
            h.z = f2bf(xv[k].z); h.w = f2bf(xv[k].w);
            *(ushort4*)&H0[rr*72 + c4] = h;
            if (task > 0 && c4 < 32) {
                VT[(c4+0)*72 + rr] = h.x;
                VT[(c4+1)*72 + rr] = h.y;
                VT[(c4+2)*72 + rr] = h.z;
                VT[(c4+3)*72 + rr] = h.w;
            }
        }
        // W layers 0,1 -> Wt0,Wt1 (layer 2 regs wv[8..11] staged later)
        #pragma unroll
        for (int k = 0; k < 8; ++k) {
            int idx = k*256 + tid;
            int rest = idx & 1023;
            int d = rest >> 4, c4 = (rest & 15) * 4;
            unsigned short* Wl = (idx >> 10) ? Wt1 : Wt0;
            Wl[(c4+0)*72 + d] = f2bf(wv[k].x);
            Wl[(c4+1)*72 + d] = f2bf(wv[k].y);
            Wl[(c4+2)*72 + d] = f2bf(wv[k].z);
            Wl[(c4+3)*72 + d] = f2bf(wv[k].w);
        }
        // task-0 blocks zero the output region for their tile
        if (task == 0) {
            float4 z = make_float4(0.f, 0.f, 0.f, 0.f);
            ((float4*)out)[bid*512 + tid] = z;
            ((float4*)out)[bid*512 + 256 + tid] = z;
        }
        // dense timestamps (fp32, never through bf16)
        if (task > 0 && tid < 64)
            ws[TD_OFF + rowoff[mm] + row0 + tid] = X[(size_t)(row0 + tid)*64 + 63];
        __syncthreads();

        // fire-and-forget V^T chunk store (bf16); hides under MFMA layers
        if (task > 0) {
            unsigned short* VBg = (unsigned short*)(ws + VB_OFF)
                                + (size_t)(spoffc[mm] + rb) * 2048;
            #pragma unroll
            for (int k = 0; k < 2; ++k) {
                int p = k*256 + tid;
                int e = p >> 4, j4 = (p & 15) * 4;
                *(ushort4*)&VBg[p*4] = *(ushort4*)&VT[e*72 + j4];
            }
        }

        // layer 0: H0 -> H1 (Wt0)
        mlp_layer(H0, H1, Wt0, bias0, true, nullptr, col, lm, q);
        __syncthreads();

        // stage layer-2 W into Wt0 (all reads of layer-0 W are done)
        #pragma unroll
        for (int k = 0; k < 4; ++k) {
            int idx = k*256 + tid;
            int rest = idx & 1023;
            int d = rest >> 4, c4 = (rest & 15) * 4;
            Wt0[(c4+0)*72 + d] = f2bf(wv[8+k].x);
            Wt0[(c4+1)*72 + d] = f2bf(wv[8+k].y);
            Wt0[(c4+2)*72 + d] = f2bf(wv[8+k].z);
            Wt0[(c4+3)*72 + d] = f2bf(wv[8+k].w);
        }
        // layer 1: H1 -> H0 (Wt1)
        mlp_layer(H1, H0, Wt1, bias1, true, nullptr, col, lm, q);
        __syncthreads();

        // layer 2: H0 -> H1 (Wt0), mirror K^T for chunk sum
        mlp_layer(H0, H1, Wt0, bias2, false, (task > 0) ? KT : nullptr,
                  col, lm, q);
        __syncthreads();

        // coalesced bf16 global store of final activations (H1)
        {
            unsigned short* dst = (task == 0)
                ? (unsigned short*)(ws + QB_OFF)
                : (unsigned short*)(ws + KB_OFF) + (size_t)rowoff[mm]*64;
            #pragma unroll
            for (int k = 0; k < 4; ++k) {
                int idx = k*256 + tid;
                int rr = idx >> 4, c4 = (idx & 15) * 4;
                *(ushort4*)&dst[(size_t)(row0 + rr)*64 + c4] = *(ushort4*)&H1[rr*72 + c4];
            }
        }

        // chunk sum S[d][e] = sum_j K[j][d] V[j][e]; wave w owns d-tile w
        if (task > 0) {
            unsigned short* slotH = (unsigned short*)(ws + SP_OFF)
                                  + (size_t)(spoffc[mm] + rb) * 2048;
            #pragma unroll
            for (int nt = 0; nt < 2; ++nt) {
                floatx4 acc = {0.f, 0.f, 0.f, 0.f};
                #pragma unroll
                for (int ks = 0; ks < 2; ++ks) {
                    short8 aa = *(const short8*)&KT[col*72 + ks*32 + q*8];
                    short8 bb = *(const short8*)&VT[(nt*16+lm)*72 + ks*32 + q*8];
                    acc = MFMA16(aa, bb, acc);
                }
                #pragma unroll
                for (int r = 0; r < 4; ++r)
                    slotH[(w*16 + q*4 + r)*32 + nt*16 + lm] = f2bf(acc[r]);
            }
        }

        // publish: __syncthreads drains this block's stores (vmcnt(0) before
        // s_barrier); the agent-scope RELEASE store performs the dirty-L2
        // writeback to the LLC and then publishes MAGIC. ONE cache op per
        // block -- no extra __threadfence_system (R6's double writeback).
        __syncthreads();
        if (tid == 0) {
            int fi = (task == 0) ? bid : (64 + spoffc[mm] + rb);
            __hip_atomic_store(&flags[fi], MAGIC, __ATOMIC_RELEASE,
                               __HIP_MEMORY_SCOPE_AGENT);
        }
    }

    // ================= Phase C: tiled MFMA query =================
    {
        unsigned short* qs = SH;                 // Q  [i][d]
        unsigned short* kc = SH + 4608;          // K  [j][d]  (chunk)
        unsigned short* ps = SH + 9216;          // masked P [i][j]
        unsigned short* vt = SH + 13824;         // V^T [e][j] (2304)
        unsigned short* st = SH + 16128;         // S^T [e][d] (2304)
        float* tq  = SF;                         // t1 tile (fp32!)
        float* tcs = SF + 64;                    // t2 chunk (fp32!)

        const int m    = bid & 3;
        const int tile = (bid >> 2) & 63;
        const int slot = bid >> 8;               // 0 or 1
        const int i0   = tile * 64;
        const int nch  = nchv[m];

        // spin only on the flags this block needs:
        //   tid<nch          -> chunk flags of module m (covers Kb/SP/VB/TD_m)
        //   tid==254         -> qflag[tile] (Q rows + out-zero of this tile)
        //   tid==255         -> m1 chunk flag[tile] (t1/TD region)
        // RELAXED spin loads (no per-iteration cache ops!); ONE acquire fence
        // per block after exit.
        {
            int fidx = -1;
            if (tid < nch)       fidx = 64 + spoffc[m] + tid;
            else if (tid == 254) fidx = tile;
            else if (tid == 255) fidx = 64 + tile;
            bool ok = (fidx < 0);
            while (true) {
                if (!ok && __hip_atomic_load(&flags[fidx], __ATOMIC_RELAXED,
                                             __HIP_MEMORY_SCOPE_AGENT) == MAGIC)
                    ok = true;
                if (__syncthreads_and(ok ? 1 : 0)) break;
                __builtin_amdgcn_s_sleep(8);
            }
            __threadfence();   // single acquire: invalidate stale L2 lines
        }

        const unsigned short* Qg  = (const unsigned short*)(ws + QB_OFF);
        const unsigned short* Kg  = (const unsigned short*)(ws + KB_OFF) + (size_t)rowoff[m]*64;
        const unsigned short* SPH = (const unsigned short*)(ws + SP_OFF);
        const unsigned short* VBH = (const unsigned short*)(ws + VB_OFF);
        const float* td = ws + TD_OFF;

        // Q tile -> LDS
        #pragma unroll
        for (int k = 0; k < 4; ++k) {
            int idx = k*256 + tid;
            int rr = idx >> 4, c4 = (idx & 15) * 4;
            *(ushort4*)&qs[rr*72 + c4] = *(const ushort4*)&Qg[(size_t)(i0 + rr)*64 + c4];
        }
        if (tid < 64) tq[tid] = td[i0 + tid];

        // wave-parallel 64-ary searchsorted(t2, t, side='right'):
        // wave0 -> c_lo (t = t1[i0]), wave1 -> c_hi (t = t1[i0+63]).
        if (w < 2) {
            float t = td[i0 + (w ? 63 : 0)];
            const float* t2 = td + rowoff[m];
            int lo = 0, hi = Tm[m];
            while (hi - lo > 64) {
                int step = (hi - lo + 63) >> 6;
                int pos = lo + lane*step;
                bool pred = (pos < hi) && (t2[pos] <= t);
                int c = __popcll(__ballot(pred));
                int nhi = (c < 64) ? (lo + c*step) : hi;
                if (nhi > hi) nhi = hi;
                if (c) lo = lo + (c-1)*step + 1;
                hi = nhi;
            }
            int pos = lo + lane;
            bool pred = (pos < hi) && (t2[pos] <= t);
            int c = __popcll(__ballot(pred));
            if (lane == 0) SB[w] = lo + c;
        }
        __syncthreads();

        const int c_lo = SB[0];
        const int c_hi = SB[1];
        const int B0   = c_lo >> 6;
        const int Bhi  = (c_hi + 63) >> 6;

        // NOTE: no slot-1 early return! Slot-1 owns the odd-indexed half of
        // the distributed S-prefix (R4/R5 bug).

        // on-the-fly S-prefix: sum chunk slots {slot, slot+2, ...} < B0.
        // Thread owns 8 consecutive entries (one uint4 per slot); 8 in flight.
        {
            float sacc[8] = {0.f,0.f,0.f,0.f,0.f,0.f,0.f,0.f};
            const unsigned short* sp0 = SPH + (size_t)spoffc[m]*2048 + tid*8;
#define ACC8(pv) do { \
            sacc[0] += bf2f((unsigned short)((pv).x & 0xffffu)); \
            sacc[1] += bf2f((unsigned short)((pv).x >> 16)); \
            sacc[2] += bf2f((unsigned short)((pv).y & 0xffffu)); \
            sacc[3] += bf2f((unsigned short)((pv).y >> 16)); \
            sacc[4] += bf2f((unsigned short)((pv).z & 0xffffu)); \
            sacc[5] += bf2f((unsigned short)((pv).z >> 16)); \
            sacc[6] += bf2f((unsigned short)((pv).w & 0xffffu)); \
            sacc[7] += bf2f((unsigned short)((pv).w >> 16)); \
        } while (0)
            int k = slot;
            for (; k + 14 < B0; k += 16) {
                uint4 p0 = *(const uint4*)(sp0 + (size_t)(k   )*2048);
                uint4 p1 = *(const uint4*)(sp0 + (size_t)(k+ 2)*2048);
                uint4 p2 = *(const uint4*)(sp0 + (size_t)(k+ 4)*2048);
                uint4 p3 = *(const uint4*)(sp0 + (size_t)(k+ 6)*2048);
                uint4 p4 = *(const uint4*)(sp0 + (size_t)(k+ 8)*2048);
                uint4 p5 = *(const uint4*)(sp0 + (size_t)(k+10)*2048);
                uint4 p6 = *(const uint4*)(sp0 + (size_t)(k+12)*2048);
                uint4 p7 = *(const uint4*)(sp0 + (size_t)(k+14)*2048);
                ACC8(p0); ACC8(p1); ACC8(p2); ACC8(p3);
                ACC8(p4); ACC8(p5); ACC8(p6); ACC8(p7);
            }
            for (; k + 6 < B0; k += 8) {
                uint4 p0 = *(const uint4*)(sp0 + (size_t)(k  )*2048);
                uint4 p1 = *(const uint4*)(sp0 + (size_t)(k+2)*2048);
                uint4 p2 = *(const uint4*)(sp0 + (size_t)(k+4)*2048);
                uint4 p3 = *(const uint4*)(sp0 + (size_t)(k+6)*2048);
                ACC8(p0); ACC8(p1); ACC8(p2); ACC8(p3);
            }
            for (; k < B0; k += 2) {
                uint4 p0 = *(const uint4*)(sp0 + (size_t)k*2048);
                ACC8(p0);
            }
#undef ACC8
            int d0 = (tid*8) >> 5, e0 = (tid*8) & 31;
            #pragma unroll
            for (int k2 = 0; k2 < 8; ++k2)
                st[(e0+k2)*72 + d0] = f2bf(sacc[k2]);
        }
        __syncthreads();

        float t1v[16];
        #pragma unroll
        for (int mt = 0; mt < 4; ++mt)
            #pragma unroll
            for (int r = 0; r < 4; ++r)
                t1v[mt*4 + r] = tq[mt*16 + q*4 + r];

        short8 qa[4][2];
        #pragma unroll
        for (int mt = 0; mt < 4; ++mt) {
            qa[mt][0] = *(const short8*)&qs[(mt*16+lm)*72 + q*8];
            qa[mt][1] = *(const short8*)&qs[(mt*16+lm)*72 + 32 + q*8];
        }

        floatx4 accO[2];
        accO[0] = (floatx4){0.f, 0.f, 0.f, 0.f};
        accO[1] = (floatx4){0.f, 0.f, 0.f, 0.f};

        // Q . S_partial (both slots; each holds its half of the prefix)
        #pragma unroll
        for (int nt = 0; nt < 2; ++nt) {
            #pragma unroll
            for (int ks = 0; ks < 2; ++ks) {
                short8 b = *(const short8*)&st[(nt*16+lm)*72 + ks*32 + q*8];
                accO[nt] = MFMA16(qa[w][ks], b, accO[nt]);
            }
        }

        // boundary chunks: masked attention, odd/even split across slots
        // (loop is naturally empty for slot-1 blocks with <2 boundary chunks)
        #pragma unroll 1
        for (int B = B0 + slot; B < Bhi; B += 2) {
            __syncthreads();
            #pragma unroll
            for (int k = 0; k < 4; ++k) {
                int idx = k*256 + tid;
                int j = idx >> 4, c4 = (idx & 15) * 4;
                *(ushort4*)&kc[j*72 + c4] = *(const ushort4*)&Kg[(size_t)(B*64 + j)*64 + c4];
            }
            {
                const unsigned short* VBg = VBH + (size_t)(spoffc[m] + B)*2048;
                #pragma unroll
                for (int k = 0; k < 2; ++k) {
                    int p = k*256 + tid;
                    int e = p >> 4, j4 = (p & 15) * 4;
                    *(ushort4*)&vt[e*72 + j4] = *(const ushort4*)&VBg[p*4];
                }
            }
            if (tid < 64) tcs[tid] = td[rowoff[m] + B*64 + tid];
            __syncthreads();

            {
                short8 bk0 = *(const short8*)&kc[(w*16+lm)*72 + q*8];
                short8 bk1 = *(const short8*)&kc[(w*16+lm)*72 + 32 + q*8];
                float t2j = tcs[w*16 + lm];
                #pragma unroll
                for (int mt = 0; mt < 4; ++mt) {
                    floatx4 f = {0.f, 0.f, 0.f, 0.f};
                    f = MFMA16(qa[mt][0], bk0, f);
                    f = MFMA16(qa[mt][1], bk1, f);
                    #pragma unroll
                    for (int r = 0; r < 4; ++r) {
                        float pv = (t2j <= t1v[mt*4 + r]) ? f[r] : 0.0f;
                        ps[(mt*16 + q*4 + r)*72 + w*16 + lm] = f2bf(pv);
                    }
                }
            }
            __syncthreads();

            {
                short8 pa0 = *(const short8*)&ps[(w*16+lm)*72 + q*8];
                short8 pa1 = *(const short8*)&ps[(w*16+lm)*72 + 32 + q*8];
                #pragma unroll
                for (int nt = 0; nt < 2; ++nt) {
                    short8 bv0 = *(const short8*)&vt[(nt*16+lm)*72 + q*8];
                    short8 bv1 = *(const short8*)&vt[(nt*16+lm)*72 + 32 + q*8];
                    accO[nt] = MFMA16(pa0, bv0, accO[nt]);
                    accO[nt] = MFMA16(pa1, bv1, accO[nt]);
                }
            }
        }

        #pragma unroll
        for (int nt = 0; nt < 2; ++nt)
            #pragma unroll
            for (int r = 0; r < 4; ++r) {
                int i = w*16 + q*4 + r;
                int e = nt*16 + lm;
                atomicAdd(&out[(size_t)(i0 + i)*32 + e], accO[nt][r]);
            }
    }
}

extern "C" void kernel_launch(void* const* d_in, const int* in_sizes, int n_in,
                              void* d_out, int out_size, void* d_ws, size_t ws_size,
                              hipStream_t stream) {
    const float* x0   = (const float*)d_in[0];
    const float* x1   = (const float*)d_in[1];
    const float* x2   = (const float*)d_in[2];
    const float* x3   = (const float*)d_in[3];
    const float* wq_w = (const float*)d_in[4];
    const float* wq_b = (const float*)d_in[5];
    const float* wk_w = (const float*)d_in[6];
    const float* wk_b = (const float*)d_in[7];
    float* ws  = (float*)d_ws;
    float* out = (float*)d_out;

    hipLaunchKernelGGL(k_all, dim3(512), dim3(256), 0, stream,
                       x0, x1, x2, x3, wq_w, wq_b, wk_w, wk_b, ws, out);
}

// Round 8
// 98.906 us; speedup vs baseline: 1.7509x; 1.4080x over previous
//
#include <hip/hip_runtime.h>

// Problem constants
//   m1:(1,1,4096,64) m2:(1,1,6144,64) m3:(1,1,8192,64) m4:(1,1,4096,64) fp32
//   WQ_w:(3,64,64) WQ_b:(3,64) WK_w:(4,3,64,64) WK_b:(4,3,64)
//   out:(1,4096,32) fp32
//
// Two dispatches (VERIFIED best @98.3us, R3). Single-kernel fusion was tried
// three ways and measured WORSE on this runtime/chip:
//   - cooperative grid.sync: ~75us/sync (R1)
//   - per-chunk flag spin, acquire-per-poll: L2-inv storm, k_all 107us (R6)
//   - per-chunk flag spin, relaxed-poll: LLC atomic saturation, 72us (R7)
// The ~10us dispatch boundary is cheaper than any intra-kernel sync here.
//
//   k_fused : MLPs + bf16 Q/K stores + bf16 per-chunk K^T.V sums + bf16 V^T
//             chunk store (VB) + t2 dense + zero out.
//   k_query : per-block wave-parallel searchsorted (c_lo/c_hi) + on-the-fly
//             S-prefix column-sum (slot 0/1 each sum half the chunks) +
//             boundary-chunk masked attention (K,V both bf16 from ws) +
//             atomicAdd.
//
// Workspace layout (float units):
//   Qb   bf16 [4096][64]                 @ 0          (131072 fl)
//   Kb   bf16 per module [T_m][64]       @ 131072     (720896 fl)
//   SP   bf16 352 slots x 2048 (d*32+e)  @ 851968     (360448 fl)
//   VB   bf16 352 slots x 2048 (e*64+j)  @ 1212416    (360448 fl)
//   TD   fp32 dense t2 per module        @ 1581056    (22528 fl)

#define QB_OFF   0
#define KB_OFF   131072
#define SP_OFF   851968
#define VB_OFF   1212416
#define TD_OFF   1581056

typedef __attribute__((ext_vector_type(8))) short short8;    // bf16 frag (4 VGPR)
typedef __attribute__((ext_vector_type(4))) float floatx4;   // MFMA C/D

__device__ __forceinline__ unsigned short f2bf(float f) {
    union { float f; unsigned u; } v; v.f = f;
    unsigned r = v.u + 0x7fff + ((v.u >> 16) & 1);   // RNE
    return (unsigned short)(r >> 16);
}
__device__ __forceinline__ float bf2f(unsigned short h) {
    union { unsigned u; float f; } v; v.u = ((unsigned)h) << 16;
    return v.f;
}

#define MFMA16(a,b,c) __builtin_amdgcn_mfma_f32_16x16x32_bf16((a),(b),(c),0,0,0)

// ---------------------------------------------------------------------------
// Fused: 3-layer MLP (bf16 MFMA) + bf16 Q/K store + bf16 chunk K^T.V sums +
// bf16 V^T chunk store + out zeroing. 64-row tiles -> 416 blocks. One explicit
// register batch of global loads (X tile + all 3 W layers) up front; V^T
// staged from those registers (no tail global re-read); VB store issued right
// after the first barrier so its latency hides under the MFMA layers.
__global__ __launch_bounds__(256) void k_fused(
    const float* __restrict__ x0, const float* __restrict__ x1,
    const float* __restrict__ x2, const float* __restrict__ x3,
    const float* __restrict__ wq_w, const float* __restrict__ wq_b,
    const float* __restrict__ wk_w, const float* __restrict__ wk_b,
    float* __restrict__ ws, float* __restrict__ out)
{
    __shared__ unsigned short H0[64*72];      // act ping [row][col]
    __shared__ unsigned short H1[64*72];      // act pong
    __shared__ unsigned short Wt[3][64*72];   // W^T all layers [c][d]
    __shared__ unsigned short KT[64*72];      // K^T [d][j]
    __shared__ unsigned short VT[32*72];      // V^T [e][j]

    const int tid = threadIdx.x;
    const int bid = blockIdx.x;

    int task, rb;
    if (bid < 64)       { task = 0; rb = bid; }
    else if (bid < 128) { task = 1; rb = bid - 64; }
    else if (bid < 224) { task = 2; rb = bid - 128; }
    else if (bid < 352) { task = 3; rb = bid - 224; }
    else                { task = 4; rb = bid - 352; }

    const float* Xs[4] = {x0, x1, x2, x3};
    const int rowoff[4] = {0, 4096, 10240, 18432};
    const int spoffc[4] = {0, 64, 160, 288};      // chunk-slot base per module

    const float* X; const float* W; const float* Bv; int mm = -1;
    if (task == 0) { X = x0; W = wq_w; Bv = wq_b; }
    else {
        mm = task - 1;
        X = Xs[mm]; W = wk_w + mm*3*64*64; Bv = wk_b + mm*3*64;
    }

    const int row0 = rb * 64;

    // ---- one up-front register batch: X tile + all 3 W layers ----
    {
        const float4* X4 = (const float4*)(X + (size_t)row0*64);
        float4 xv[4];
        #pragma unroll
        for (int k = 0; k < 4; ++k) xv[k] = X4[k*256 + tid];
        const float4* W4 = (const float4*)W;
        float4 wv[12];
        #pragma unroll
        for (int k = 0; k < 12; ++k) wv[k] = W4[k*256 + tid];

        // X -> H0 [row][col] bf16, and V^T [e][j] for e<32 from the same regs
        #pragma unroll
        for (int k = 0; k < 4; ++k) {
            int idx = k*256 + tid;            // 0..1023 float4s
            int rr = idx >> 4, c4 = (idx & 15) * 4;
            ushort4 h;
            h.x = f2bf(xv[k].x); h.y = f2bf(xv[k].y);
            h.z = f2bf(xv[k].z); h.w = f2bf(xv[k].w);
            *(ushort4*)&H0[rr*72 + c4] = h;
            if (task > 0 && c4 < 32) {
                VT[(c4+0)*72 + rr] = h.x;
                VT[(c4+1)*72 + rr] = h.y;
                VT[(c4+2)*72 + rr] = h.z;
                VT[(c4+3)*72 + rr] = h.w;
            }
        }
        // W -> Wt transposed [c][d]
        #pragma unroll
        for (int k = 0; k < 12; ++k) {
            int idx = k*256 + tid;            // 0..3071 float4s over 3 layers
            int l = idx >> 10, rest = idx & 1023;
            int d = rest >> 4, c4 = (rest & 15) * 4;
            Wt[l][(c4+0)*72 + d] = f2bf(wv[k].x);
            Wt[l][(c4+1)*72 + d] = f2bf(wv[k].y);
            Wt[l][(c4+2)*72 + d] = f2bf(wv[k].z);
            Wt[l][(c4+3)*72 + d] = f2bf(wv[k].w);
        }
    }
    // task-0 blocks zero the output (k_query only atomicAdds)
    if (task == 0) {
        float4 z = make_float4(0.f, 0.f, 0.f, 0.f);
        ((float4*)out)[bid*512 + tid] = z;
        ((float4*)out)[bid*512 + 256 + tid] = z;
    }
    // dense timestamps (fp32, never through bf16)
    if (task > 0 && tid < 64)
        ws[TD_OFF + rowoff[mm] + row0 + tid] = X[(size_t)(row0 + tid)*64 + 63];
    __syncthreads();

    // fire-and-forget V^T chunk store (bf16); latency hides under MFMA layers
    if (task > 0) {
        unsigned short* VBg = (unsigned short*)(ws + VB_OFF)
                            + (size_t)(spoffc[mm] + rb) * 2048;
        #pragma unroll
        for (int k = 0; k < 2; ++k) {
            int p = k*256 + tid;              // 0..511 ushort4 groups
            int e = p >> 4, j4 = (p & 15) * 4;
            *(ushort4*)&VBg[p*4] = *(ushort4*)&VT[e*72 + j4];
        }
    }

    const int w    = tid >> 6;      // wave id = n-tile
    const int lane = tid & 63;
    const int lm   = lane & 15;
    const int q    = lane >> 4;
    const int col  = w*16 + lm;

    // ---- 3 MFMA layers, ONE barrier each (ping-pong) ----
    #pragma unroll 1
    for (int l = 0; l < 3; ++l) {
        const unsigned short* Hin  = (l & 1) ? H1 : H0;
        unsigned short*       Hout = (l & 1) ? H0 : H1;
        float bias = Bv[l*64 + col];
        short8 b0 = *(const short8*)&Wt[l][col*72 + q*8];
        short8 b1 = *(const short8*)&Wt[l][col*72 + 32 + q*8];
        #pragma unroll
        for (int mt = 0; mt < 4; ++mt) {
            floatx4 acc = {bias, bias, bias, bias};
            short8 a0 = *(const short8*)&Hin[(mt*16+lm)*72 + q*8];
            short8 a1 = *(const short8*)&Hin[(mt*16+lm)*72 + 32 + q*8];
            acc = MFMA16(a0, b0, acc);
            acc = MFMA16(a1, b1, acc);
            int r0 = mt*16 + q*4;
            #pragma unroll
            for (int r = 0; r < 4; ++r) {
                float f = acc[r];
                if (l < 2) f = fmaxf(f, 0.0f);
                unsigned short hb = f2bf(f);
                Hout[(r0+r)*72 + col] = hb;
                if (l == 2 && task > 0) KT[col*72 + r0 + r] = hb;  // K^T [d][j]
            }
        }
        __syncthreads();
    }

    // coalesced bf16 global store of final activations (in H1)
    {
        unsigned short* dst = (task == 0)
            ? (unsigned short*)(ws + QB_OFF)
            : (unsigned short*)(ws + KB_OFF) + (size_t)rowoff[mm]*64;
        #pragma unroll
        for (int k = 0; k < 4; ++k) {
            int idx = k*256 + tid;            // 0..1023 ushort4s
            int rr = idx >> 4, c4 = (idx & 15) * 4;
            *(ushort4*)&dst[(size_t)(row0 + rr)*64 + c4] = *(ushort4*)&H1[rr*72 + c4];
        }
    }
    if (task == 0) return;

    // chunk sum S[d][e] = sum_j K[j][d] V[j][e]; wave w owns d-tile w.
    // KT written before the last layer barrier, VT before the first: both valid.
    {
        unsigned short* slotH = (unsigned short*)(ws + SP_OFF)
                              + (size_t)(spoffc[mm] + rb) * 2048;
        #pragma unroll
        for (int nt = 0; nt < 2; ++nt) {
            floatx4 acc = {0.f, 0.f, 0.f, 0.f};
            #pragma unroll
            for (int ks = 0; ks < 2; ++ks) {
                short8 aa = *(const short8*)&KT[col*72 + ks*32 + q*8];
                short8 bb = *(const short8*)&VT[(nt*16+lm)*72 + ks*32 + q*8];
                acc = MFMA16(aa, bb, acc);
            }
            #pragma unroll
            for (int r = 0; r < 4; ++r)
                slotH[(w*16 + q*4 + r)*32 + nt*16 + lm] = f2bf(acc[r]);
        }
    }
}

// ---------------------------------------------------------------------------
// Tiled MFMA query kernel, chunk-slot split: 512 blocks = (module m, 64-query
// tile, slot in {0,1}). Self-contained: computes its own c-bounds via a
// wave-parallel 64-ary searchsorted, and its own S-prefix by column-summing
// its half of the bf16 chunk slots (4-deep load batching). K and V both come
// from ws in bf16 (no fp32 V re-read, no transpose in the chunk loop).
__global__ __launch_bounds__(256) void k_query(
    float* __restrict__ ws, float* __restrict__ out)
{
    __shared__ unsigned short qs[64*72];   // Q  [i][d]
    __shared__ unsigned short kc[64*72];   // K  [j][d]  (chunk)
    __shared__ unsigned short vt[32*72];   // V^T [e][j] (chunk)
    __shared__ unsigned short st[32*72];   // S^T [e][d] (partial prefix)
    __shared__ unsigned short ps[64*72];   // masked P [i][j] (chunk)
    __shared__ float tq[64];               // t1 tile (fp32!)
    __shared__ float tcs[64];              // t2 chunk (fp32!)
    __shared__ int   SB[2];                // c_lo, c_hi

    const int tid  = threadIdx.x;
    const int m    = blockIdx.x & 3;
    const int tile = (blockIdx.x >> 2) & 63;
    const int slot = blockIdx.x >> 8;      // 0 or 1
    const int i0   = tile * 64;

    const int w    = tid >> 6;
    const int lane = tid & 63;
    const int lm   = lane & 15;
    const int q    = lane >> 4;

    const int rowoff[4] = {0, 4096, 10240, 18432};
    const int spoffc[4] = {0, 64, 160, 288};
    const int Tm[4]     = {4096, 6144, 8192, 4096};

    const unsigned short* Qg  = (const unsigned short*)(ws + QB_OFF);
    const unsigned short* Kg  = (const unsigned short*)(ws + KB_OFF) + (size_t)rowoff[m]*64;
    const unsigned short* SPH = (const unsigned short*)(ws + SP_OFF);
    const unsigned short* VBH = (const unsigned short*)(ws + VB_OFF);
    const float* td = ws + TD_OFF;

    // Q tile -> LDS
    #pragma unroll
    for (int k = 0; k < 4; ++k) {
        int idx = k*256 + tid;
        int rr = idx >> 4, c4 = (idx & 15) * 4;
        *(ushort4*)&qs[rr*72 + c4] = *(const ushort4*)&Qg[(size_t)(i0 + rr)*64 + c4];
    }
    if (tid < 64) tq[tid] = td[i0 + tid];

    // wave-parallel 64-ary searchsorted(t2, t, side='right'):
    // wave0 -> c_lo (t = t1[i0]), wave1 -> c_hi (t = t1[i0+63]).
    if (w < 2) {
        float t = td[i0 + (w ? 63 : 0)];
        const float* t2 = td + rowoff[m];
        int lo = 0, hi = Tm[m];
        while (hi - lo > 64) {
            int step = (hi - lo + 63) >> 6;
            int pos = lo + lane*step;
            bool pred = (pos < hi) && (t2[pos] <= t);
            int c = __popcll(__ballot(pred));
            int nhi = (c < 64) ? (lo + c*step) : hi;
            if (nhi > hi) nhi = hi;
            if (c) lo = lo + (c-1)*step + 1;
            hi = nhi;
        }
        int pos = lo + lane;
        bool pred = (pos < hi) && (t2[pos] <= t);
        int c = __popcll(__ballot(pred));
        if (lane == 0) SB[w] = lo + c;
    }
    __syncthreads();

    const int c_lo = SB[0];
    const int c_hi = SB[1];
    const int B0   = c_lo >> 6;
    const int Bhi  = (c_hi + 63) >> 6;

    // on-the-fly S-prefix: this block sums chunk slots {slot, slot+2, ...} < B0.
    // Thread owns 8 consecutive entries (one uint4 per slot); 4 loads in flight.
    // NOTE: no slot-1 early return anywhere -- slot-1 owns the odd-indexed
    // half of the distributed prefix (R4/R5 lesson).
    {
        float sacc[8] = {0.f,0.f,0.f,0.f,0.f,0.f,0.f,0.f};
        const unsigned short* sp0 = SPH + (size_t)spoffc[m]*2048 + tid*8;
#define ACC8(pv) do { \
            sacc[0] += bf2f((unsigned short)((pv).x & 0xffffu)); \
            sacc[1] += bf2f((unsigned short)((pv).x >> 16)); \
            sacc[2] += bf2f((unsigned short)((pv).y & 0xffffu)); \
            sacc[3] += bf2f((unsigned short)((pv).y >> 16)); \
            sacc[4] += bf2f((unsigned short)((pv).z & 0xffffu)); \
            sacc[5] += bf2f((unsigned short)((pv).z >> 16)); \
            sacc[6] += bf2f((unsigned short)((pv).w & 0xffffu)); \
            sacc[7] += bf2f((unsigned short)((pv).w >> 16)); \
        } while (0)
        int k = slot;
        for (; k + 6 < B0; k += 8) {
            uint4 p0 = *(const uint4*)(sp0 + (size_t)(k  )*2048);
            uint4 p1 = *(const uint4*)(sp0 + (size_t)(k+2)*2048);
            uint4 p2 = *(const uint4*)(sp0 + (size_t)(k+4)*2048);
            uint4 p3 = *(const uint4*)(sp0 + (size_t)(k+6)*2048);
            ACC8(p0); ACC8(p1); ACC8(p2); ACC8(p3);
        }
        for (; k < B0; k += 2) {
            uint4 p0 = *(const uint4*)(sp0 + (size_t)k*2048);
            ACC8(p0);
        }
#undef ACC8
        int d0 = (tid*8) >> 5, e0 = (tid*8) & 31;   // 8 consecutive e, same d
        #pragma unroll
        for (int k2 = 0; k2 < 8; ++k2)
            st[(e0+k2)*72 + d0] = f2bf(sacc[k2]);
    }
    __syncthreads();

    float t1v[16];
    #pragma unroll
    for (int mt = 0; mt < 4; ++mt)
        #pragma unroll
        for (int r = 0; r < 4; ++r)
            t1v[mt*4 + r] = tq[mt*16 + q*4 + r];

    short8 qa[4][2];
    #pragma unroll
    for (int mt = 0; mt < 4; ++mt) {
        qa[mt][0] = *(const short8*)&qs[(mt*16+lm)*72 + q*8];
        qa[mt][1] = *(const short8*)&qs[(mt*16+lm)*72 + 32 + q*8];
    }

    floatx4 accO[2];
    accO[0] = (floatx4){0.f, 0.f, 0.f, 0.f};
    accO[1] = (floatx4){0.f, 0.f, 0.f, 0.f};

    // Q . S_partial (both slots; each holds its half of the prefix)
    #pragma unroll
    for (int nt = 0; nt < 2; ++nt) {
        #pragma unroll
        for (int ks = 0; ks < 2; ++ks) {
            short8 b = *(const short8*)&st[(nt*16+lm)*72 + ks*32 + q*8];
            accO[nt] = MFMA16(qa[w][ks], b, accO[nt]);
        }
    }

    // boundary chunks: masked attention, odd/even split across slots
    #pragma unroll 1
    for (int B = B0 + slot; B < Bhi; B += 2) {
        __syncthreads();
        #pragma unroll
        for (int k = 0; k < 4; ++k) {
            int idx = k*256 + tid;
            int j = idx >> 4, c4 = (idx & 15) * 4;
            *(ushort4*)&kc[j*72 + c4] = *(const ushort4*)&Kg[(size_t)(B*64 + j)*64 + c4];
        }
        {
            const unsigned short* VBg = VBH + (size_t)(spoffc[m] + B)*2048;
            #pragma unroll
            for (int k = 0; k < 2; ++k) {
                int p = k*256 + tid;          // 0..511 ushort4 groups
                int e = p >> 4, j4 = (p & 15) * 4;
                *(ushort4*)&vt[e*72 + j4] = *(const ushort4*)&VBg[p*4];
            }
        }
        if (tid < 64) tcs[tid] = td[rowoff[m] + B*64 + tid];
        __syncthreads();

        {
            short8 bk0 = *(const short8*)&kc[(w*16+lm)*72 + q*8];
            short8 bk1 = *(const short8*)&kc[(w*16+lm)*72 + 32 + q*8];
            float t2j = tcs[w*16 + lm];
            #pragma unroll
            for (int mt = 0; mt < 4; ++mt) {
                floatx4 f = {0.f, 0.f, 0.f, 0.f};
                f = MFMA16(qa[mt][0], bk0, f);
                f = MFMA16(qa[mt][1], bk1, f);
                #pragma unroll
                for (int r = 0; r < 4; ++r) {
                    float p = (t2j <= t1v[mt*4 + r]) ? f[r] : 0.0f;
                    ps[(mt*16 + q*4 + r)*72 + w*16 + lm] = f2bf(p);
                }
            }
        }
        __syncthreads();

        {
            short8 pa0 = *(const short8*)&ps[(w*16+lm)*72 + q*8];
            short8 pa1 = *(const short8*)&ps[(w*16+lm)*72 + 32 + q*8];
            #pragma unroll
            for (int nt = 0; nt < 2; ++nt) {
                short8 bv0 = *(const short8*)&vt[(nt*16+lm)*72 + q*8];
                short8 bv1 = *(const short8*)&vt[(nt*16+lm)*72 + 32 + q*8];
                accO[nt] = MFMA16(pa0, bv0, accO[nt]);
                accO[nt] = MFMA16(pa1, bv1, accO[nt]);
            }
        }
    }

    #pragma unroll
    for (int nt = 0; nt < 2; ++nt)
        #pragma unroll
        for (int r = 0; r < 4; ++r) {
            int i = w*16 + q*4 + r;
            int e = nt*16 + lm;
            atomicAdd(&out[(size_t)(i0 + i)*32 + e], accO[nt][r]);
        }
}

extern "C" void kernel_launch(void* const* d_in, const int* in_sizes, int n_in,
                              void* d_out, int out_size, void* d_ws, size_t ws_size,
                              hipStream_t stream) {
    const float* x0   = (const float*)d_in[0];
    const float* x1   = (const float*)d_in[1];
    const float* x2   = (const float*)d_in[2];
    const float* x3   = (const float*)d_in[3];
    const float* wq_w = (const float*)d_in[4];
    const float* wq_b = (const float*)d_in[5];
    const float* wk_w = (const float*)d_in[6];
    const float* wk_b = (const float*)d_in[7];
    float* ws  = (float*)d_ws;
    float* out = (float*)d_out;

    hipLaunchKernelGGL(k_fused, dim3(416), dim3(256), 0, stream,
                       x0, x1, x2, x3, wq_w, wq_b, wk_w, wk_b, ws, out);
    hipLaunchKernelGGL(k_query, dim3(512), dim3(256), 0, stream, ws, out);
}